// Round 7
// baseline (251.413 us; speedup 1.0000x reference)
//
#include <hip/hip_runtime.h>
#include <hip/hip_bf16.h>
#include <stdint.h>

// ---------------------------------------------------------------------------
// Single-head self-attention, B=4, S=2048, D=1024, fp32 in/out.
// Round 14: NEW k_qkv — rebuilt on the harness-proven 256^2 4-phase skeleton
// (the round-1/2/5 k_score engine: 8 waves of 128x64, acc[8][4], BK=64,
// 128KB dbuf LDS, row-XOR swizzle, vmcnt 12->4 ledger, setprio), with qkv's
// epilogue re-indexed for 2 passes (bias+store q/k; vT transpose for z==2).
// Grid 384 = 32tm x (3z x 4tn), 1 blk/CU, 1.5 rounds; each XCD owns 4
// tm-slabs x 12 zn-tiles (A-slab L2 reuse). k_score (round-6 engine 256x128),
// k_pv (known-good 128^2), k_prep unchanged.
// Pipeline (4 dispatches):
//   1. k_prep:  xb=bf16(x); wt=bf16(W^T); rowsum=0
//   2. k_qkv:   q,k = x@W+b (bf16); v -> vT transposed  [256^2 4-phase]
//   3. k_score: P' = exp2(q@k^T*s*log2e) (bf16) + rowsum  [engine 256x128]
//   4. k_pv:    out = (P' @ vT^T)/rowsum (fp32 -> d_out)  [128x128 2-barrier]
// ---------------------------------------------------------------------------

typedef __attribute__((ext_vector_type(8))) short short8;   // 8 bf16 = 4 VGPR
typedef __attribute__((ext_vector_type(4))) float f32x4;    // MFMA C/D

__device__ __forceinline__ unsigned short f2bf(float f) {
  union { float f; uint32_t u; } c; c.f = f;
  uint32_t u = c.u;
  u += 0x7FFFu + ((u >> 16) & 1u);   // RNE
  return (unsigned short)(u >> 16);
}

// async global->LDS, 16B/lane; LDS dest is wave-uniform base + lane*16.
__device__ __forceinline__ void gl16(const void* g, void* l) {
  __builtin_amdgcn_global_load_lds(
      (const __attribute__((address_space(1))) unsigned int*)g,
      (__attribute__((address_space(3))) unsigned int*)l, 16, 0, 0);
}

#define FENCE() asm volatile("" ::: "memory")
#define BARRIER() do { FENCE(); __builtin_amdgcn_s_barrier(); FENCE(); } while (0)
#define VMWAIT(n) asm volatile("s_waitcnt vmcnt(" #n ")" ::: "memory")

// ---------------- k_qkv: 256x256 tile, 512 thr, 4-phase pipeline -----------
// q,k,v = x@W+b. M=8192, N=3x1024, K=1024, BK=64 (16 K-tiles).
// 384 blocks = 32 tm x 12 zn; 128KB LDS; waves 2x4 of 128x64.
__global__ __launch_bounds__(512, 2) void k_qkv(
    const short* __restrict__ A, const short* __restrict__ B,
    short* __restrict__ Cb, short* __restrict__ vT,
    const float* __restrict__ b0, const float* __restrict__ b1,
    const float* __restrict__ b2)
{
  __shared__ short lds[65536];   // 128 KB

  const int b = blockIdx.x;          // 384
  const int xcd = b & 7, r = b >> 3; // r 0..47
  const int tm = xcd * 4 + r / 12;   // 0..31 (each XCD: 4 consecutive slabs)
  const int zn = r % 12;
  const int z = zn >> 2, tn = zn & 3;

  const int tid = threadIdx.x;
  const int lane = tid & 63;
  const int wid = tid >> 6;               // 0..7
  const int fr = lane & 15, quad = lane >> 4, frk = fr & 7;
  const int wm = wid >> 2, wn = wid & 3;  // wave: rows wm*128.., cols wn*64..

  const long tileM = (long)tm * 256;
  const long tileN = (long)tn * 256;
  const short* Az = A;
  const short* Bz = B + (long)z * 1048576L;

  // staging: chunk c -> (row=c>>3, slot=(c&7)^(row&7)); +64-row strides keep
  // the same slot.
  const int srow = tid >> 3;
  const int sslot = (tid & 7) ^ (srow & 7);
  const short* gA = Az + (tileM + srow) * 1024 + sslot * 8;
  const short* gB = Bz + (tileN + srow) * 1024 + sslot * 8;

  // fragment read offsets (shorts); row&7 == fr&7 (row blocks are x16)
  const int aBase = wm << 13;             // wm*128 rows * 64 shorts
  const int bBase = 16384 + (wn << 12);   // B region + wn*64 rows
  const int o0 = ((quad ^ frk) << 3) + (fr << 6);        // kk=0 slot
  const int o1 = (((quad + 4) ^ frk) << 3) + (fr << 6);  // kk=1 slot

  f32x4 acc[8][4] = {};

  auto stageA = [&](int tt) {          // 4 loads: 256 rows of A tile tt
    const short* s = gA + tt * 64;
    short* d = &lds[(tt & 1) << 15];
    gl16(s,          d + (tid << 3));
    gl16(s + 65536,  d + 4096 + (tid << 3));
    gl16(s + 131072, d + 8192 + (tid << 3));
    gl16(s + 196608, d + 12288 + (tid << 3));
  };
  auto stageBh = [&](int tt, int h) {  // 2 loads: B rows h*128..h*128+127
    const short* s = gB + tt * 64 + h * 131072;
    short* d = &lds[((tt & 1) << 15) + 16384 + (h << 13)];
    gl16(s,         d + (tid << 3));
    gl16(s + 65536, d + 4096 + (tid << 3));
  };

  // prologue: A0(4) B0(4) A1(4); drain oldest 8, keep A1 in flight
  stageA(0); stageBh(0, 0); stageBh(0, 1); stageA(1);
  VMWAIT(4);
  BARRIER();

#pragma unroll 1
  for (int t = 0; t < 16; ++t) {
    const int bb = (t & 1) << 15;
    short8 af0[4][2], af1[4][2], bf0[2][2], bf1[2][2];

    // ---- phase 0: rows 0-63 x cols 0-31 (of wave tile)
#pragma unroll
    for (int i = 0; i < 4; ++i) {
      af0[i][0] = *(const short8*)&lds[bb + aBase + (i << 10) + o0];
      af0[i][1] = *(const short8*)&lds[bb + aBase + (i << 10) + o1];
    }
#pragma unroll
    for (int j = 0; j < 2; ++j) {
      bf0[j][0] = *(const short8*)&lds[bb + bBase + (j << 10) + o0];
      bf0[j][1] = *(const short8*)&lds[bb + bBase + (j << 10) + o1];
    }
    if (t + 1 < 16) stageBh(t + 1, 0);
    BARRIER();
    __builtin_amdgcn_s_setprio(1);
#pragma unroll
    for (int i = 0; i < 4; ++i)
#pragma unroll
      for (int j = 0; j < 2; ++j) {
        acc[i][j] = __builtin_amdgcn_mfma_f32_16x16x32_bf16(af0[i][0], bf0[j][0], acc[i][j], 0, 0, 0);
        acc[i][j] = __builtin_amdgcn_mfma_f32_16x16x32_bf16(af0[i][1], bf0[j][1], acc[i][j], 0, 0, 0);
      }
    __builtin_amdgcn_s_setprio(0);
    BARRIER();

    // ---- phase 1: rows 64-127 x cols 0-31
#pragma unroll
    for (int i = 0; i < 4; ++i) {
      af1[i][0] = *(const short8*)&lds[bb + aBase + ((i + 4) << 10) + o0];
      af1[i][1] = *(const short8*)&lds[bb + aBase + ((i + 4) << 10) + o1];
    }
    if (t + 1 < 16) stageBh(t + 1, 1);
    BARRIER();
    __builtin_amdgcn_s_setprio(1);
#pragma unroll
    for (int i = 0; i < 4; ++i)
#pragma unroll
      for (int j = 0; j < 2; ++j) {
        acc[i + 4][j] = __builtin_amdgcn_mfma_f32_16x16x32_bf16(af1[i][0], bf0[j][0], acc[i + 4][j], 0, 0, 0);
        acc[i + 4][j] = __builtin_amdgcn_mfma_f32_16x16x32_bf16(af1[i][1], bf0[j][1], acc[i + 4][j], 0, 0, 0);
      }
    __builtin_amdgcn_s_setprio(0);
    BARRIER();

    // ---- phase 2: rows 64-127 x cols 32-63
#pragma unroll
    for (int j = 0; j < 2; ++j) {
      bf1[j][0] = *(const short8*)&lds[bb + bBase + ((j + 2) << 10) + o0];
      bf1[j][1] = *(const short8*)&lds[bb + bBase + ((j + 2) << 10) + o1];
    }
    BARRIER();
    __builtin_amdgcn_s_setprio(1);
#pragma unroll
    for (int i = 0; i < 4; ++i)
#pragma unroll
      for (int j = 0; j < 2; ++j) {
        acc[i + 4][j + 2] = __builtin_amdgcn_mfma_f32_16x16x32_bf16(af1[i][0], bf1[j][0], acc[i + 4][j + 2], 0, 0, 0);
        acc[i + 4][j + 2] = __builtin_amdgcn_mfma_f32_16x16x32_bf16(af1[i][1], bf1[j][1], acc[i + 4][j + 2], 0, 0, 0);
      }
    __builtin_amdgcn_s_setprio(0);
    BARRIER();

    // ---- phase 3: rows 0-63 x cols 32-63; stage A(t+2)
    if (t + 2 < 16) stageA(t + 2);
    BARRIER();
    __builtin_amdgcn_s_setprio(1);
#pragma unroll
    for (int i = 0; i < 4; ++i)
#pragma unroll
      for (int j = 0; j < 2; ++j) {
        acc[i][j + 2] = __builtin_amdgcn_mfma_f32_16x16x32_bf16(af0[i][0], bf1[j][0], acc[i][j + 2], 0, 0, 0);
        acc[i][j + 2] = __builtin_amdgcn_mfma_f32_16x16x32_bf16(af0[i][1], bf1[j][1], acc[i][j + 2], 0, 0, 0);
      }
    __builtin_amdgcn_s_setprio(0);
    if (t < 14) { VMWAIT(4); } else { VMWAIT(0); }
    BARRIER();
  }

  __syncthreads();
  // C/D layout: row=(lane>>4)*4+rr, col=lane&15. Two passes of 64 rows.
  short* scr = &lds[wid * 4608];   // [64][72] per wave
  if (z == 2) {
    // v-tile: bias, transposed scratch [d][t], store vT[b][d][t]
    const int gb = tm >> 3;
#pragma unroll
    for (int pass = 0; pass < 2; ++pass) {
#pragma unroll
      for (int j = 0; j < 4; ++j) {
        const float bv = b2[tileN + wn * 64 + j * 16 + fr];
#pragma unroll
        for (int i = 0; i < 4; ++i)
#pragma unroll
          for (int rr = 0; rr < 4; ++rr)
            scr[(j * 16 + fr) * 72 + i * 16 + quad * 4 + rr] =
                (short)f2bf(acc[pass * 4 + i][j][rr] + bv);
      }
      const long t0 = (long)(tm & 7) * 256 + wm * 128 + pass * 64;
#pragma unroll
      for (int c = 0; c < 8; ++c) {
        const int rr = c * 8 + (lane >> 3);
        const int cc = (lane & 7) * 8;
        short8 v = *(const short8*)&scr[rr * 72 + cc];
        const long gd = tileN + wn * 64 + rr;
        *(short8*)(vT + ((long)gb << 21) + gd * 2048 + t0 + cc) = v;
      }
      if (pass == 0) __syncthreads();   // scratch WAR between passes
    }
  } else {
    short* C = Cb + (long)z * 8388608L;
    const float* bias = (z == 0) ? b0 : b1;
#pragma unroll
    for (int pass = 0; pass < 2; ++pass) {
#pragma unroll
      for (int j = 0; j < 4; ++j) {
        const float bv = bias[tileN + wn * 64 + j * 16 + fr];
#pragma unroll
        for (int i = 0; i < 4; ++i)
#pragma unroll
          for (int rr = 0; rr < 4; ++rr)
            scr[(i * 16 + quad * 4 + rr) * 72 + j * 16 + fr] =
                (short)f2bf(acc[pass * 4 + i][j][rr] + bv);
      }
#pragma unroll
      for (int c = 0; c < 8; ++c) {
        const int row = c * 8 + (lane >> 3);
        const int col = (lane & 7) * 8;
        short8 v = *(const short8*)&scr[row * 72 + col];
        *(short8*)(C + (tileM + wm * 128 + pass * 64 + row) * 1024 +
                   tileN + wn * 64 + col) = v;
      }
      if (pass == 0) __syncthreads();   // scratch WAR between passes
    }
  }
}

// ---------------- k_score: 256x128 tile, 512 thr, 2-phase engine -----------
// P' = exp2(q@k^T * scale) bf16 + rowsum atomics. Per z: M=2048, N=2048,
// K=1024, BK=64 (16 K-tiles). Grid 512 = 8tm x 16tn x 4z.
__global__ __launch_bounds__(512, 2) void k_score(
    const short* __restrict__ A, const short* __restrict__ B,
    short* __restrict__ Pp, float scale, float* __restrict__ rowsum)
{
  __shared__ short lds[49152];   // 96 KB

  const int b = blockIdx.x;          // 512
  const int xcd = b & 7, r = b >> 3; // r 0..63
  const int slab = xcd * 4 + (r >> 4);   // 0..31: (z,tm), 4 per XCD
  const int tn = r & 15;
  const int z = slab >> 3, tm = slab & 7;

  const int tid = threadIdx.x;
  const int lane = tid & 63;
  const int wid = tid >> 6;               // 0..7
  const int fr = lane & 15, quad = lane >> 4, frk = fr & 7;
  const int wm = wid >> 1, wn = wid & 1;  // wave: rows wm*64.., cols wn*64..

  const long tileM = (long)tm * 256;
  const long tileN = (long)tn * 128;
  const short* Az = A + (long)z * 2097152L;   // q [2048][1024]
  const short* Bz = B + (long)z * 2097152L;   // k [2048][1024]

  const int srow = tid >> 3;
  const int sslot = (tid & 7) ^ (srow & 7);
  const short* gA = Az + (tileM + srow) * 1024 + sslot * 8;
  const short* gB = Bz + (tileN + srow) * 1024 + sslot * 8;

  const int aBase = wm << 12;             // wm*64 rows * 64 shorts
  const int bBase = 16384 + (wn << 12);   // B region + wn*64 rows
  const int o0 = ((quad ^ frk) << 3) + (fr << 6);        // kk=0 slot
  const int o1 = (((quad + 4) ^ frk) << 3) + (fr << 6);  // kk=1 slot

  f32x4 acc[4][4] = {};

  auto stageA = [&](int tt) {          // 4 loads: 256 rows of A tile tt
    const short* s = gA + tt * 64;
    short* d = &lds[(tt & 1) * 24576];
    gl16(s,          d + (tid << 3));
    gl16(s + 65536,  d + 4096 + (tid << 3));
    gl16(s + 131072, d + 8192 + (tid << 3));
    gl16(s + 196608, d + 12288 + (tid << 3));
  };
  auto stageB = [&](int tt) {          // 2 loads: 128 rows of B tile tt
    const short* s = gB + tt * 64;
    short* d = &lds[(tt & 1) * 24576 + 16384];
    gl16(s,         d + (tid << 3));
    gl16(s + 65536, d + 4096 + (tid << 3));
  };

  // prologue: A0(4) B0(2) A1(4); drain A0+B0, keep A1 in flight
  stageA(0); stageB(0); stageA(1);
  VMWAIT(4);
  BARRIER();

#pragma unroll 1
  for (int t = 0; t < 16; ++t) {
    const int bb = (t & 1) * 24576;
    short8 af[4][2], bf0[2][2], bf1[2][2];

    // ---- phase 0: all rows x cols 0-31 (of wave tile)
#pragma unroll
    for (int i = 0; i < 4; ++i) {
      af[i][0] = *(const short8*)&lds[bb + aBase + (i << 10) + o0];
      af[i][1] = *(const short8*)&lds[bb + aBase + (i << 10) + o1];
    }
#pragma unroll
    for (int j = 0; j < 2; ++j) {
      bf0[j][0] = *(const short8*)&lds[bb + bBase + (j << 10) + o0];
      bf0[j][1] = *(const short8*)&lds[bb + bBase + (j << 10) + o1];
    }
    if (t + 1 < 16) stageB(t + 1);
    BARRIER();
    __builtin_amdgcn_s_setprio(1);
#pragma unroll
    for (int i = 0; i < 4; ++i)
#pragma unroll
      for (int j = 0; j < 2; ++j) {
        acc[i][j] = __builtin_amdgcn_mfma_f32_16x16x32_bf16(af[i][0], bf0[j][0], acc[i][j], 0, 0, 0);
        acc[i][j] = __builtin_amdgcn_mfma_f32_16x16x32_bf16(af[i][1], bf0[j][1], acc[i][j], 0, 0, 0);
      }
    __builtin_amdgcn_s_setprio(0);
    BARRIER();

    // ---- phase 1: all rows x cols 32-63; stage A(t+2)
#pragma unroll
    for (int j = 0; j < 2; ++j) {
      bf1[j][0] = *(const short8*)&lds[bb + bBase + ((j + 2) << 10) + o0];
      bf1[j][1] = *(const short8*)&lds[bb + bBase + ((j + 2) << 10) + o1];
    }
    if (t + 2 < 16) stageA(t + 2);
    BARRIER();
    __builtin_amdgcn_s_setprio(1);
#pragma unroll
    for (int i = 0; i < 4; ++i)
#pragma unroll
      for (int j = 0; j < 2; ++j) {
        acc[i][j + 2] = __builtin_amdgcn_mfma_f32_16x16x32_bf16(af[i][0], bf1[j][0], acc[i][j + 2], 0, 0, 0);
        acc[i][j + 2] = __builtin_amdgcn_mfma_f32_16x16x32_bf16(af[i][1], bf1[j][1], acc[i][j + 2], 0, 0, 0);
      }
    __builtin_amdgcn_s_setprio(0);
    if (t < 14) { VMWAIT(4); } else { VMWAIT(0); }
    BARRIER();
  }

  // ---- epilogue: exp2, rowsum, bf16 transpose store ----
#pragma unroll
  for (int i = 0; i < 4; ++i)
#pragma unroll
    for (int j = 0; j < 4; ++j)
#pragma unroll
      for (int r = 0; r < 4; ++r)
        acc[i][j][r] = exp2f(acc[i][j][r] * scale);

  float* rsz = rowsum + (long)z * 2048 + tileM + wm * 64;
#pragma unroll
  for (int i = 0; i < 4; ++i)
#pragma unroll
    for (int r = 0; r < 4; ++r) {
      float s = acc[i][0][r] + acc[i][1][r] + acc[i][2][r] + acc[i][3][r];
      s += __shfl_xor(s, 1);
      s += __shfl_xor(s, 2);
      s += __shfl_xor(s, 4);
      s += __shfl_xor(s, 8);
      if (fr == 0) atomicAdd(&rsz[i * 16 + quad * 4 + r], s);
    }

  __syncthreads();
  short* C = Pp + (long)z * 4194304L;
  short* scr = &lds[wid * 4608];   // [64][72] per wave
#pragma unroll
  for (int j = 0; j < 4; ++j)
#pragma unroll
    for (int i = 0; i < 4; ++i)
#pragma unroll
      for (int r = 0; r < 4; ++r)
        scr[(i * 16 + quad * 4 + r) * 72 + j * 16 + fr] =
            (short)f2bf(acc[i][j][r]);
#pragma unroll
  for (int c = 0; c < 8; ++c) {
    const int row = c * 8 + (lane >> 3);
    const int col = (lane & 7) * 8;
    short8 v = *(const short8*)&scr[row * 72 + col];
    *(short8*)(C + (tileM + wm * 64 + row) * 2048 + tileN + wn * 64 + col) = v;
  }
}

// ----------------- k_pv: 128x128, 256 thr, swizzled (known-good) -----------
// out = (P' @ vT^T) / rowsum, fp32. K=2048, BK=32 dbuf. Grid 512.
__global__ __launch_bounds__(256) void k_pv(
    const short* __restrict__ A, const short* __restrict__ B,
    float* __restrict__ Cf, float* __restrict__ rowsum)
{
  const int b = blockIdx.x;
  const int s = b & 7, r0_ = b >> 3;
  const int z = r0_ >> 4;
  const int mem = r0_ & 15;
  const int tm = (s >> 1) * 4 + (mem >> 2);
  const int tn = (s & 1) * 4 + (mem & 3);

  __shared__ short lds[18432];

  const int tid  = threadIdx.x;
  const int lane = tid & 63;
  const int wid  = tid >> 6;
  const long tileM = (long)tm * 128;
  const long tileN = (long)tn * 128;
  const short* Az = A + (long)z * 4194304L;
  const short* Bz = B + (long)z * 2097152L;

  const int c0 = tid, c1 = 256 + tid;
  const short* gA0 = Az + (tileM + (c0 >> 2)) * 2048 + (c0 & 3) * 8;
  const short* gA1 = Az + (tileM + (c1 >> 2)) * 2048 + (c1 & 3) * 8;
  const short* gB0 = Bz + (tileN + (c0 >> 2)) * 2048 + (c0 & 3) * 8;
  const short* gB1 = Bz + (tileN + (c1 >> 2)) * 2048 + (c1 & 3) * 8;

  const int fr = lane & 15, quad = lane >> 4;
  const int waveM = (wid >> 1) * 64, waveN = (wid & 1) * 64;

  f32x4 acc[4][4] = {};

  {
    short* base = lds;
    gl16(gA0, base + c0 * 8);
    gl16(gA1, base + c1 * 8);
    gl16(gB0, base + 4096 + c0 * 8);
    gl16(gB1, base + 4096 + c1 * 8);
  }

  for (int t = 0; t < 64; ++t) {
    __syncthreads();
    if (t + 1 < 64) {
      const int kt = (t + 1) << 5;
      short* base = lds + ((t + 1) & 1) * 8192;
      gl16(gA0 + kt, base + c0 * 8);
      gl16(gA1 + kt, base + c1 * 8);
      gl16(gB0 + kt, base + 4096 + c0 * 8);
      gl16(gB1 + kt, base + 4096 + c1 * 8);
    }
    const short* sA = lds + (t & 1) * 8192;
    const short* sB = sA + 4096;
    short8 af[4], bf[4];
#pragma unroll
    for (int i = 0; i < 4; ++i)
      af[i] = *(const short8*)&sA[(waveM + i * 16 + fr) * 32 + quad * 8];
#pragma unroll
    for (int j = 0; j < 4; ++j)
      bf[j] = *(const short8*)&sB[(waveN + j * 16 + fr) * 32 + quad * 8];
#pragma unroll
    for (int i = 0; i < 4; ++i)
#pragma unroll
      for (int j = 0; j < 4; ++j)
        acc[i][j] = __builtin_amdgcn_mfma_f32_16x16x32_bf16(af[i], bf[j],
                                                            acc[i][j], 0, 0, 0);
  }

  float* C = Cf + (long)z * 2097152L;
#pragma unroll
  for (int i = 0; i < 4; ++i)
#pragma unroll
    for (int r = 0; r < 4; ++r) {
      const long gr = tileM + waveM + i * 16 + quad * 4 + r;
      const float rinv = 1.0f / rowsum[(long)z * 2048 + gr];
#pragma unroll
      for (int j = 0; j < 4; ++j)
        C[gr * 1024 + tileN + waveN + j * 16 + fr] = acc[i][j][r] * rinv;
    }
}

// prep: blocks [0,8192) cvt x -> bf16; [8192,11264) W^T -> bf16; 11264 zero rs
__global__ __launch_bounds__(256) void k_prep(
    const float4* __restrict__ x, ushort4* __restrict__ xb,
    const float* __restrict__ Wq, const float* __restrict__ Wk,
    const float* __restrict__ Wv, short* __restrict__ WT,
    float* __restrict__ rs)
{
  __shared__ short tile[32][33];
  const int b = blockIdx.x;
  if (b < 8192) {
    const long i = (long)b * 256 + threadIdx.x;
    float4 v = x[i];
    ushort4 o;
    o.x = f2bf(v.x); o.y = f2bf(v.y); o.z = f2bf(v.z); o.w = f2bf(v.w);
    xb[i] = o;
  } else if (b < 11264) {
    const int idx = b - 8192;
    const int z = idx >> 10, rem = idx & 1023;
    const float* W = (z == 0) ? Wq : ((z == 1) ? Wk : Wv);
    short* d = WT + (long)z * 1024 * 1024;
    const int n0 = (rem & 31) * 32, d0 = (rem >> 5) * 32;
    const int tx = threadIdx.x & 31, ty = threadIdx.x >> 5;
#pragma unroll
    for (int p = 0; p < 4; ++p)
      tile[ty + p * 8][tx] = (short)f2bf(W[(long)(d0 + ty + p * 8) * 1024 + n0 + tx]);
    __syncthreads();
#pragma unroll
    for (int p = 0; p < 4; ++p)
      d[(long)(n0 + ty + p * 8) * 1024 + d0 + tx] = tile[tx][ty + p * 8];
  } else {
#pragma unroll
    for (int p = 0; p < 32; ++p)
      rs[p * 256 + threadIdx.x] = 0.0f;
  }
}

extern "C" void kernel_launch(void* const* d_in, const int* in_sizes, int n_in,
                              void* d_out, int out_size, void* d_ws, size_t ws_size,
                              hipStream_t stream) {
  const float* x  = (const float*)d_in[0];
  const float* Wq = (const float*)d_in[1];
  const float* bq = (const float*)d_in[2];
  const float* Wk = (const float*)d_in[3];
  const float* bk = (const float*)d_in[4];
  const float* Wv = (const float*)d_in[5];
  const float* bv = (const float*)d_in[6];

  char* ws = (char*)d_ws;
  short* xb  = (short*)(ws);                  // 16 MB
  short* wt  = (short*)(ws + 16777216);       // 6 MB
  short* qkv = (short*)(ws + 23068672);       // 48 MB: q | k | vT
  short* Pp  = (short*)(ws + 73400320);       // 32 MB: [4][2048][2048] bf16
  float* rs  = (float*)(ws + 106954752);      // 32 KB: [4][2048] fp32
  short* vT  = qkv + 2L * 8388608;            // [4][1024][2048] bf16

  // 1. prep: xb, wt, rowsum=0
  k_prep<<<11265, 256, 0, stream>>>((const float4*)x, (ushort4*)xb,
                                    Wq, Wk, Wv, wt, rs);
  // 2. q,k = x@W+b (bf16); v written transposed into vT  [256^2 4-phase]
  k_qkv<<<384, 512, 0, stream>>>(xb, wt, qkv, vT, bq, bk, bv);
  // 3. P' = exp2(q@k^T * scale*log2e), bf16 + rowsum  [engine 256x128]
  k_score<<<512, 512, 0, stream>>>(qkv, qkv + 8388608, Pp,
                                   0.03125f * 1.44269504088896f, rs);
  // 4. out = (P' @ vT^T) / rowsum  (fp32 -> d_out)
  k_pv<<<512, 256, 0, stream>>>(Pp, vT, (float*)d_out, rs);
}

// Round 8
// 248.486 us; speedup vs baseline: 1.0118x; 1.0118x over previous
//
#include <hip/hip_runtime.h>
#include <hip/hip_bf16.h>
#include <stdint.h>

// ---------------------------------------------------------------------------
// Single-head self-attention, B=4, S=2048, D=1024, fp32 in/out.
// Round 15: k_score REVERTED to the round-1/2-verified 4-phase 256^2 engine
// (acc[8][4], 8 waves of 128x64, BK=64, 128KB dbuf, vmcnt(4), setprio).
// Rationale from round-7 counters: 384-block qkv ran 2 quantized rounds of
// 37us/tile => the 4-phase engine is 929 TF per-CU (vs 673 for 2-phase);
// score's 256-block grid packs that rate perfectly (1 round, 0% idle).
// k_qkv keeps the round-7 4-phase 256^2 (74us, FETCH 60MB; its 1.5-round
// grid quantizes to 2 rounds — structural, not fixable at this tile size).
// k_pv (known-good 128^2), k_prep unchanged.
// Pipeline (4 dispatches):
//   1. k_prep:  xb=bf16(x); wt=bf16(W^T); rowsum=0
//   2. k_qkv:   q,k = x@W+b (bf16); v -> vT transposed  [256^2 4-phase]
//   3. k_score: P' = exp2(q@k^T*s*log2e) (bf16) + rowsum  [256^2 4-phase]
//   4. k_pv:    out = (P' @ vT^T)/rowsum (fp32 -> d_out)  [128x128 2-barrier]
// ---------------------------------------------------------------------------

typedef __attribute__((ext_vector_type(8))) short short8;   // 8 bf16 = 4 VGPR
typedef __attribute__((ext_vector_type(4))) float f32x4;    // MFMA C/D

__device__ __forceinline__ unsigned short f2bf(float f) {
  union { float f; uint32_t u; } c; c.f = f;
  uint32_t u = c.u;
  u += 0x7FFFu + ((u >> 16) & 1u);   // RNE
  return (unsigned short)(u >> 16);
}

// async global->LDS, 16B/lane; LDS dest is wave-uniform base + lane*16.
__device__ __forceinline__ void gl16(const void* g, void* l) {
  __builtin_amdgcn_global_load_lds(
      (const __attribute__((address_space(1))) unsigned int*)g,
      (__attribute__((address_space(3))) unsigned int*)l, 16, 0, 0);
}

#define FENCE() asm volatile("" ::: "memory")
#define BARRIER() do { FENCE(); __builtin_amdgcn_s_barrier(); FENCE(); } while (0)
#define VMWAIT(n) asm volatile("s_waitcnt vmcnt(" #n ")" ::: "memory")

// ---------------- k_qkv: 256x256 tile, 512 thr, 4-phase pipeline -----------
// q,k,v = x@W+b. M=8192, N=3x1024, K=1024, BK=64 (16 K-tiles).
// 384 blocks = 32 tm x 12 zn; 128KB LDS; waves 2x4 of 128x64.
__global__ __launch_bounds__(512, 2) void k_qkv(
    const short* __restrict__ A, const short* __restrict__ B,
    short* __restrict__ Cb, short* __restrict__ vT,
    const float* __restrict__ b0, const float* __restrict__ b1,
    const float* __restrict__ b2)
{
  __shared__ short lds[65536];   // 128 KB

  const int b = blockIdx.x;          // 384
  const int xcd = b & 7, r = b >> 3; // r 0..47
  const int tm = xcd * 4 + r / 12;   // 0..31 (each XCD: 4 consecutive slabs)
  const int zn = r % 12;
  const int z = zn >> 2, tn = zn & 3;

  const int tid = threadIdx.x;
  const int lane = tid & 63;
  const int wid = tid >> 6;               // 0..7
  const int fr = lane & 15, quad = lane >> 4, frk = fr & 7;
  const int wm = wid >> 2, wn = wid & 3;  // wave: rows wm*128.., cols wn*64..

  const long tileM = (long)tm * 256;
  const long tileN = (long)tn * 256;
  const short* Az = A;
  const short* Bz = B + (long)z * 1048576L;

  // staging: chunk c -> (row=c>>3, slot=(c&7)^(row&7)); +64-row strides keep
  // the same slot.
  const int srow = tid >> 3;
  const int sslot = (tid & 7) ^ (srow & 7);
  const short* gA = Az + (tileM + srow) * 1024 + sslot * 8;
  const short* gB = Bz + (tileN + srow) * 1024 + sslot * 8;

  // fragment read offsets (shorts); row&7 == fr&7 (row blocks are x16)
  const int aBase = wm << 13;             // wm*128 rows * 64 shorts
  const int bBase = 16384 + (wn << 12);   // B region + wn*64 rows
  const int o0 = ((quad ^ frk) << 3) + (fr << 6);        // kk=0 slot
  const int o1 = (((quad + 4) ^ frk) << 3) + (fr << 6);  // kk=1 slot

  f32x4 acc[8][4] = {};

  auto stageA = [&](int tt) {          // 4 loads: 256 rows of A tile tt
    const short* s = gA + tt * 64;
    short* d = &lds[(tt & 1) << 15];
    gl16(s,          d + (tid << 3));
    gl16(s + 65536,  d + 4096 + (tid << 3));
    gl16(s + 131072, d + 8192 + (tid << 3));
    gl16(s + 196608, d + 12288 + (tid << 3));
  };
  auto stageBh = [&](int tt, int h) {  // 2 loads: B rows h*128..h*128+127
    const short* s = gB + tt * 64 + h * 131072;
    short* d = &lds[((tt & 1) << 15) + 16384 + (h << 13)];
    gl16(s,         d + (tid << 3));
    gl16(s + 65536, d + 4096 + (tid << 3));
  };

  // prologue: A0(4) B0(4) A1(4); drain oldest 8, keep A1 in flight
  stageA(0); stageBh(0, 0); stageBh(0, 1); stageA(1);
  VMWAIT(4);
  BARRIER();

#pragma unroll 1
  for (int t = 0; t < 16; ++t) {
    const int bb = (t & 1) << 15;
    short8 af0[4][2], af1[4][2], bf0[2][2], bf1[2][2];

    // ---- phase 0: rows 0-63 x cols 0-31 (of wave tile)
#pragma unroll
    for (int i = 0; i < 4; ++i) {
      af0[i][0] = *(const short8*)&lds[bb + aBase + (i << 10) + o0];
      af0[i][1] = *(const short8*)&lds[bb + aBase + (i << 10) + o1];
    }
#pragma unroll
    for (int j = 0; j < 2; ++j) {
      bf0[j][0] = *(const short8*)&lds[bb + bBase + (j << 10) + o0];
      bf0[j][1] = *(const short8*)&lds[bb + bBase + (j << 10) + o1];
    }
    if (t + 1 < 16) stageBh(t + 1, 0);
    BARRIER();
    __builtin_amdgcn_s_setprio(1);
#pragma unroll
    for (int i = 0; i < 4; ++i)
#pragma unroll
      for (int j = 0; j < 2; ++j) {
        acc[i][j] = __builtin_amdgcn_mfma_f32_16x16x32_bf16(af0[i][0], bf0[j][0], acc[i][j], 0, 0, 0);
        acc[i][j] = __builtin_amdgcn_mfma_f32_16x16x32_bf16(af0[i][1], bf0[j][1], acc[i][j], 0, 0, 0);
      }
    __builtin_amdgcn_s_setprio(0);
    BARRIER();

    // ---- phase 1: rows 64-127 x cols 0-31
#pragma unroll
    for (int i = 0; i < 4; ++i) {
      af1[i][0] = *(const short8*)&lds[bb + aBase + ((i + 4) << 10) + o0];
      af1[i][1] = *(const short8*)&lds[bb + aBase + ((i + 4) << 10) + o1];
    }
    if (t + 1 < 16) stageBh(t + 1, 1);
    BARRIER();
    __builtin_amdgcn_s_setprio(1);
#pragma unroll
    for (int i = 0; i < 4; ++i)
#pragma unroll
      for (int j = 0; j < 2; ++j) {
        acc[i + 4][j] = __builtin_amdgcn_mfma_f32_16x16x32_bf16(af1[i][0], bf0[j][0], acc[i + 4][j], 0, 0, 0);
        acc[i + 4][j] = __builtin_amdgcn_mfma_f32_16x16x32_bf16(af1[i][1], bf0[j][1], acc[i + 4][j], 0, 0, 0);
      }
    __builtin_amdgcn_s_setprio(0);
    BARRIER();

    // ---- phase 2: rows 64-127 x cols 32-63
#pragma unroll
    for (int j = 0; j < 2; ++j) {
      bf1[j][0] = *(const short8*)&lds[bb + bBase + ((j + 2) << 10) + o0];
      bf1[j][1] = *(const short8*)&lds[bb + bBase + ((j + 2) << 10) + o1];
    }
    BARRIER();
    __builtin_amdgcn_s_setprio(1);
#pragma unroll
    for (int i = 0; i < 4; ++i)
#pragma unroll
      for (int j = 0; j < 2; ++j) {
        acc[i + 4][j + 2] = __builtin_amdgcn_mfma_f32_16x16x32_bf16(af1[i][0], bf1[j][0], acc[i + 4][j + 2], 0, 0, 0);
        acc[i + 4][j + 2] = __builtin_amdgcn_mfma_f32_16x16x32_bf16(af1[i][1], bf1[j][1], acc[i + 4][j + 2], 0, 0, 0);
      }
    __builtin_amdgcn_s_setprio(0);
    BARRIER();

    // ---- phase 3: rows 0-63 x cols 32-63; stage A(t+2)
    if (t + 2 < 16) stageA(t + 2);
    BARRIER();
    __builtin_amdgcn_s_setprio(1);
#pragma unroll
    for (int i = 0; i < 4; ++i)
#pragma unroll
      for (int j = 0; j < 2; ++j) {
        acc[i][j + 2] = __builtin_amdgcn_mfma_f32_16x16x32_bf16(af0[i][0], bf1[j][0], acc[i][j + 2], 0, 0, 0);
        acc[i][j + 2] = __builtin_amdgcn_mfma_f32_16x16x32_bf16(af0[i][1], bf1[j][1], acc[i][j + 2], 0, 0, 0);
      }
    __builtin_amdgcn_s_setprio(0);
    if (t < 14) { VMWAIT(4); } else { VMWAIT(0); }
    BARRIER();
  }

  __syncthreads();
  // C/D layout: row=(lane>>4)*4+rr, col=lane&15. Two passes of 64 rows.
  short* scr = &lds[wid * 4608];   // [64][72] per wave
  if (z == 2) {
    // v-tile: bias, transposed scratch [d][t], store vT[b][d][t]
    const int gb = tm >> 3;
#pragma unroll
    for (int pass = 0; pass < 2; ++pass) {
#pragma unroll
      for (int j = 0; j < 4; ++j) {
        const float bv = b2[tileN + wn * 64 + j * 16 + fr];
#pragma unroll
        for (int i = 0; i < 4; ++i)
#pragma unroll
          for (int rr = 0; rr < 4; ++rr)
            scr[(j * 16 + fr) * 72 + i * 16 + quad * 4 + rr] =
                (short)f2bf(acc[pass * 4 + i][j][rr] + bv);
      }
      const long t0 = (long)(tm & 7) * 256 + wm * 128 + pass * 64;
#pragma unroll
      for (int c = 0; c < 8; ++c) {
        const int rr = c * 8 + (lane >> 3);
        const int cc = (lane & 7) * 8;
        short8 v = *(const short8*)&scr[rr * 72 + cc];
        const long gd = tileN + wn * 64 + rr;
        *(short8*)(vT + ((long)gb << 21) + gd * 2048 + t0 + cc) = v;
      }
      if (pass == 0) __syncthreads();   // scratch WAR between passes
    }
  } else {
    short* C = Cb + (long)z * 8388608L;
    const float* bias = (z == 0) ? b0 : b1;
#pragma unroll
    for (int pass = 0; pass < 2; ++pass) {
#pragma unroll
      for (int j = 0; j < 4; ++j) {
        const float bv = bias[tileN + wn * 64 + j * 16 + fr];
#pragma unroll
        for (int i = 0; i < 4; ++i)
#pragma unroll
          for (int rr = 0; rr < 4; ++rr)
            scr[(i * 16 + quad * 4 + rr) * 72 + j * 16 + fr] =
                (short)f2bf(acc[pass * 4 + i][j][rr] + bv);
      }
#pragma unroll
      for (int c = 0; c < 8; ++c) {
        const int row = c * 8 + (lane >> 3);
        const int col = (lane & 7) * 8;
        short8 v = *(const short8*)&scr[row * 72 + col];
        *(short8*)(C + (tileM + wm * 128 + pass * 64 + row) * 1024 +
                   tileN + wn * 64 + col) = v;
      }
      if (pass == 0) __syncthreads();   // scratch WAR between passes
    }
  }
}

// ---------------- k_score: 256x256 tile, 512 thr, 4-phase pipeline ---------
// P' = exp2(q@k^T * scale) bf16 + rowsum atomics. K=1024, BK=64.
// Grid 256 blocks (1/CU, exactly 1 round): xcd=b&7; 32 (z,tm) slabs x 8 tn.
// Round-1/2-verified source (byte-identical).
__global__ __launch_bounds__(512, 2) void k_score(
    const short* __restrict__ A, const short* __restrict__ B,
    short* __restrict__ Pp, float scale, float* __restrict__ rowsum)
{
  __shared__ short lds[65536];   // 128 KB

  const int b = blockIdx.x;
  const int xcd = b & 7, jb = b >> 3;
  const int p = xcd * 4 + (jb >> 3);   // 32 (z,tm) slabs, 4 per XCD
  const int tn = jb & 7;
  const int z = p >> 3, tm = p & 7;

  const int tid = threadIdx.x;
  const int lane = tid & 63;
  const int wid = tid >> 6;            // 0..7
  const int fr = lane & 15, quad = lane >> 4;
  const int wm = wid >> 2, wn = wid & 3;   // wave owns rows wm*128.., cols wn*64..

  const long tileM = (long)tm * 256;
  const long tileN = (long)tn * 256;
  const short* Az = A + (long)z * 2097152L;
  const short* Bz = B + (long)z * 2097152L;

  const int srow = tid >> 3;
  const int sslot = (tid & 7) ^ (srow & 7);
  const short* gA = Az + (tileM + srow) * 1024 + sslot * 8;
  const short* gB = Bz + (tileN + srow) * 1024 + sslot * 8;

  const int frk = fr & 7;
  const int aBase = wm << 13;                                 // own A half
  const int bRow  = 16384 + ((wn >> 1) << 13) + ((wn & 1) << 12); // own B half+64
  const int o0 = ((quad ^ frk) << 3) + (fr << 6);             // kk=0 slot
  const int o1 = (((quad + 4) ^ frk) << 3) + (fr << 6);       // kk=1 slot

  f32x4 acc[8][4] = {};

  auto stageA = [&](int tt) {          // 4 loads: both halves of A tile tt
    const short* s = gA + tt * 64;
    short* d = &lds[(tt & 1) << 15];
    gl16(s,          d + (tid << 3));
    gl16(s + 65536,  d + 4096 + (tid << 3));
    gl16(s + 131072, d + 8192 + (tid << 3));
    gl16(s + 196608, d + 12288 + (tid << 3));
  };
  auto stageBh = [&](int tt, int h) {  // 2 loads: B half h of tile tt
    const short* s = gB + tt * 64 + h * 131072;
    short* d = &lds[((tt & 1) << 15) + 16384 + (h << 13)];
    gl16(s,         d + (tid << 3));
    gl16(s + 65536, d + 4096 + (tid << 3));
  };

  // prologue: A0(4) B0(4) A1(4); drain oldest 8, keep A1 in flight
  stageA(0); stageBh(0, 0); stageBh(0, 1); stageA(1);
  VMWAIT(4);
  BARRIER();

#pragma unroll 1
  for (int t = 0; t < 16; ++t) {
    const int bb = (t & 1) << 15;
    short8 af0[4][2], af1[4][2], bf0[2][2], bf1[2][2];

    // ---- phase 0: quadrant rows 0-63 x cols 0-31 (of wave tile)
#pragma unroll
    for (int i = 0; i < 4; ++i) {
      af0[i][0] = *(const short8*)&lds[bb + aBase + (i << 10) + o0];
      af0[i][1] = *(const short8*)&lds[bb + aBase + (i << 10) + o1];
    }
#pragma unroll
    for (int j = 0; j < 2; ++j) {
      bf0[j][0] = *(const short8*)&lds[bb + bRow + (j << 10) + o0];
      bf0[j][1] = *(const short8*)&lds[bb + bRow + (j << 10) + o1];
    }
    if (t + 1 < 16) stageBh(t + 1, 0);
    BARRIER();
    __builtin_amdgcn_s_setprio(1);
#pragma unroll
    for (int i = 0; i < 4; ++i)
#pragma unroll
      for (int j = 0; j < 2; ++j) {
        acc[i][j] = __builtin_amdgcn_mfma_f32_16x16x32_bf16(af0[i][0], bf0[j][0], acc[i][j], 0, 0, 0);
        acc[i][j] = __builtin_amdgcn_mfma_f32_16x16x32_bf16(af0[i][1], bf0[j][1], acc[i][j], 0, 0, 0);
      }
    __builtin_amdgcn_s_setprio(0);
    BARRIER();

    // ---- phase 1: rows 64-127 x cols 0-31
#pragma unroll
    for (int i = 0; i < 4; ++i) {
      af1[i][0] = *(const short8*)&lds[bb + aBase + ((i + 4) << 10) + o0];
      af1[i][1] = *(const short8*)&lds[bb + aBase + ((i + 4) << 10) + o1];
    }
    if (t + 1 < 16) stageBh(t + 1, 1);
    BARRIER();
    __builtin_amdgcn_s_setprio(1);
#pragma unroll
    for (int i = 0; i < 4; ++i)
#pragma unroll
      for (int j = 0; j < 2; ++j) {
        acc[i + 4][j] = __builtin_amdgcn_mfma_f32_16x16x32_bf16(af1[i][0], bf0[j][0], acc[i + 4][j], 0, 0, 0);
        acc[i + 4][j] = __builtin_amdgcn_mfma_f32_16x16x32_bf16(af1[i][1], bf0[j][1], acc[i + 4][j], 0, 0, 0);
      }
    __builtin_amdgcn_s_setprio(0);
    BARRIER();

    // ---- phase 2: rows 64-127 x cols 32-63
#pragma unroll
    for (int j = 0; j < 2; ++j) {
      bf1[j][0] = *(const short8*)&lds[bb + bRow + ((j + 2) << 10) + o0];
      bf1[j][1] = *(const short8*)&lds[bb + bRow + ((j + 2) << 10) + o1];
    }
    BARRIER();
    __builtin_amdgcn_s_setprio(1);
#pragma unroll
    for (int i = 0; i < 4; ++i)
#pragma unroll
      for (int j = 0; j < 2; ++j) {
        acc[i + 4][j + 2] = __builtin_amdgcn_mfma_f32_16x16x32_bf16(af1[i][0], bf1[j][0], acc[i + 4][j + 2], 0, 0, 0);
        acc[i + 4][j + 2] = __builtin_amdgcn_mfma_f32_16x16x32_bf16(af1[i][1], bf1[j][1], acc[i + 4][j + 2], 0, 0, 0);
      }
    __builtin_amdgcn_s_setprio(0);
    BARRIER();

    // ---- phase 3: rows 0-63 x cols 32-63; stage A(t+2)
    if (t + 2 < 16) stageA(t + 2);
    BARRIER();
    __builtin_amdgcn_s_setprio(1);
#pragma unroll
    for (int i = 0; i < 4; ++i)
#pragma unroll
      for (int j = 0; j < 2; ++j) {
        acc[i][j + 2] = __builtin_amdgcn_mfma_f32_16x16x32_bf16(af0[i][0], bf1[j][0], acc[i][j + 2], 0, 0, 0);
        acc[i][j + 2] = __builtin_amdgcn_mfma_f32_16x16x32_bf16(af0[i][1], bf1[j][1], acc[i][j + 2], 0, 0, 0);
      }
    __builtin_amdgcn_s_setprio(0);
    if (t < 14) { VMWAIT(4); } else { VMWAIT(0); }
    BARRIER();
  }

  // exp2 (register-only)
#pragma unroll
  for (int i = 0; i < 8; ++i)
#pragma unroll
    for (int j = 0; j < 4; ++j)
#pragma unroll
      for (int r = 0; r < 4; ++r)
        acc[i][j][r] = exp2f(acc[i][j][r] * scale);

  // rowsum partials
  float* rsz = rowsum + (long)z * 2048 + tileM + wm * 128;
#pragma unroll
  for (int i = 0; i < 8; ++i)
#pragma unroll
    for (int r = 0; r < 4; ++r) {
      float s = acc[i][0][r] + acc[i][1][r] + acc[i][2][r] + acc[i][3][r];
      s += __shfl_xor(s, 1);
      s += __shfl_xor(s, 2);
      s += __shfl_xor(s, 4);
      s += __shfl_xor(s, 8);
      if (fr == 0) atomicAdd(&rsz[i * 16 + quad * 4 + r], s);
    }

  // bf16 store via per-wave LDS transpose scratch
  __syncthreads();
  short* C = Pp + (long)z * 4194304L;
  short* scr = &lds[wid * 4608];   // [64][72] per wave
#pragma unroll
  for (int pass = 0; pass < 2; ++pass) {
#pragma unroll
    for (int j = 0; j < 4; ++j)
#pragma unroll
      for (int i = 0; i < 4; ++i)
#pragma unroll
        for (int r = 0; r < 4; ++r)
          scr[(i * 16 + quad * 4 + r) * 72 + j * 16 + fr] =
              (short)f2bf(acc[pass * 4 + i][j][r]);
#pragma unroll
    for (int c = 0; c < 8; ++c) {
      const int row = c * 8 + (lane >> 3);
      const int col = (lane & 7) * 8;
      short8 v = *(const short8*)&scr[row * 72 + col];
      *(short8*)(C + (tileM + wm * 128 + pass * 64 + row) * 2048 +
                 tileN + wn * 64 + col) = v;
    }
  }
}

// ----------------- k_pv: 128x128, 256 thr, swizzled (known-good) -----------
// out = (P' @ vT^T) / rowsum, fp32. K=2048, BK=32 dbuf. Grid 512.
__global__ __launch_bounds__(256) void k_pv(
    const short* __restrict__ A, const short* __restrict__ B,
    float* __restrict__ Cf, float* __restrict__ rowsum)
{
  const int b = blockIdx.x;
  const int s = b & 7, r0_ = b >> 3;
  const int z = r0_ >> 4;
  const int mem = r0_ & 15;
  const int tm = (s >> 1) * 4 + (mem >> 2);
  const int tn = (s & 1) * 4 + (mem & 3);

  __shared__ short lds[18432];

  const int tid  = threadIdx.x;
  const int lane = tid & 63;
  const int wid  = tid >> 6;
  const long tileM = (long)tm * 128;
  const long tileN = (long)tn * 128;
  const short* Az = A + (long)z * 4194304L;
  const short* Bz = B + (long)z * 2097152L;

  const int c0 = tid, c1 = 256 + tid;
  const short* gA0 = Az + (tileM + (c0 >> 2)) * 2048 + (c0 & 3) * 8;
  const short* gA1 = Az + (tileM + (c1 >> 2)) * 2048 + (c1 & 3) * 8;
  const short* gB0 = Bz + (tileN + (c0 >> 2)) * 2048 + (c0 & 3) * 8;
  const short* gB1 = Bz + (tileN + (c1 >> 2)) * 2048 + (c1 & 3) * 8;

  const int fr = lane & 15, quad = lane >> 4;
  const int waveM = (wid >> 1) * 64, waveN = (wid & 1) * 64;

  f32x4 acc[4][4] = {};

  {
    short* base = lds;
    gl16(gA0, base + c0 * 8);
    gl16(gA1, base + c1 * 8);
    gl16(gB0, base + 4096 + c0 * 8);
    gl16(gB1, base + 4096 + c1 * 8);
  }

  for (int t = 0; t < 64; ++t) {
    __syncthreads();
    if (t + 1 < 64) {
      const int kt = (t + 1) << 5;
      short* base = lds + ((t + 1) & 1) * 8192;
      gl16(gA0 + kt, base + c0 * 8);
      gl16(gA1 + kt, base + c1 * 8);
      gl16(gB0 + kt, base + 4096 + c0 * 8);
      gl16(gB1 + kt, base + 4096 + c1 * 8);
    }
    const short* sA = lds + (t & 1) * 8192;
    const short* sB = sA + 4096;
    short8 af[4], bf[4];
#pragma unroll
    for (int i = 0; i < 4; ++i)
      af[i] = *(const short8*)&sA[(waveM + i * 16 + fr) * 32 + quad * 8];
#pragma unroll
    for (int j = 0; j < 4; ++j)
      bf[j] = *(const short8*)&sB[(waveN + j * 16 + fr) * 32 + quad * 8];
#pragma unroll
    for (int i = 0; i < 4; ++i)
#pragma unroll
      for (int j = 0; j < 4; ++j)
        acc[i][j] = __builtin_amdgcn_mfma_f32_16x16x32_bf16(af[i], bf[j],
                                                            acc[i][j], 0, 0, 0);
  }

  float* C = Cf + (long)z * 2097152L;
#pragma unroll
  for (int i = 0; i < 4; ++i)
#pragma unroll
    for (int r = 0; r < 4; ++r) {
      const long gr = tileM + waveM + i * 16 + quad * 4 + r;
      const float rinv = 1.0f / rowsum[(long)z * 2048 + gr];
#pragma unroll
      for (int j = 0; j < 4; ++j)
        C[gr * 1024 + tileN + waveN + j * 16 + fr] = acc[i][j][r] * rinv;
    }
}

// prep: blocks [0,8192) cvt x -> bf16; [8192,11264) W^T -> bf16; 11264 zero rs
__global__ __launch_bounds__(256) void k_prep(
    const float4* __restrict__ x, ushort4* __restrict__ xb,
    const float* __restrict__ Wq, const float* __restrict__ Wk,
    const float* __restrict__ Wv, short* __restrict__ WT,
    float* __restrict__ rs)
{
  __shared__ short tile[32][33];
  const int b = blockIdx.x;
  if (b < 8192) {
    const long i = (long)b * 256 + threadIdx.x;
    float4 v = x[i];
    ushort4 o;
    o.x = f2bf(v.x); o.y = f2bf(v.y); o.z = f2bf(v.z); o.w = f2bf(v.w);
    xb[i] = o;
  } else if (b < 11264) {
    const int idx = b - 8192;
    const int z = idx >> 10, rem = idx & 1023;
    const float* W = (z == 0) ? Wq : ((z == 1) ? Wk : Wv);
    short* d = WT + (long)z * 1024 * 1024;
    const int n0 = (rem & 31) * 32, d0 = (rem >> 5) * 32;
    const int tx = threadIdx.x & 31, ty = threadIdx.x >> 5;
#pragma unroll
    for (int p = 0; p < 4; ++p)
      tile[ty + p * 8][tx] = (short)f2bf(W[(long)(d0 + ty + p * 8) * 1024 + n0 + tx]);
    __syncthreads();
#pragma unroll
    for (int p = 0; p < 4; ++p)
      d[(long)(n0 + ty + p * 8) * 1024 + d0 + tx] = tile[tx][ty + p * 8];
  } else {
#pragma unroll
    for (int p = 0; p < 32; ++p)
      rs[p * 256 + threadIdx.x] = 0.0f;
  }
}

extern "C" void kernel_launch(void* const* d_in, const int* in_sizes, int n_in,
                              void* d_out, int out_size, void* d_ws, size_t ws_size,
                              hipStream_t stream) {
  const float* x  = (const float*)d_in[0];
  const float* Wq = (const float*)d_in[1];
  const float* bq = (const float*)d_in[2];
  const float* Wk = (const float*)d_in[3];
  const float* bk = (const float*)d_in[4];
  const float* Wv = (const float*)d_in[5];
  const float* bv = (const float*)d_in[6];

  char* ws = (char*)d_ws;
  short* xb  = (short*)(ws);                  // 16 MB
  short* wt  = (short*)(ws + 16777216);       // 6 MB
  short* qkv = (short*)(ws + 23068672);       // 48 MB: q | k | vT
  short* Pp  = (short*)(ws + 73400320);       // 32 MB: [4][2048][2048] bf16
  float* rs  = (float*)(ws + 106954752);      // 32 KB: [4][2048] fp32
  short* vT  = qkv + 2L * 8388608;            // [4][1024][2048] bf16

  // 1. prep: xb, wt, rowsum=0
  k_prep<<<11265, 256, 0, stream>>>((const float4*)x, (ushort4*)xb,
                                    Wq, Wk, Wv, wt, rs);
  // 2. q,k = x@W+b (bf16); v written transposed into vT  [256^2 4-phase]
  k_qkv<<<384, 512, 0, stream>>>(xb, wt, qkv, vT, bq, bk, bv);
  // 3. P' = exp2(q@k^T * scale*log2e), bf16 + rowsum  [256^2 4-phase]
  k_score<<<256, 1024 / 2, 0, stream>>>(qkv, qkv + 8388608, Pp,
                                        0.03125f * 1.44269504088896f, rs);
  // 4. out = (P' @ vT^T) / rowsum  (fp32 -> d_out)
  k_pv<<<512, 256, 0, stream>>>(Pp, vT, (float*)d_out, rs);
}

// Round 9
// 240.419 us; speedup vs baseline: 1.0457x; 1.0336x over previous
//
#include <hip/hip_runtime.h>
#include <hip/hip_bf16.h>
#include <stdint.h>

// ---------------------------------------------------------------------------
// Single-head self-attention, B=4, S=2048, D=1024, fp32 in/out.
// Round 16: k_pv engine port RETRY (3rd attempt, now on a clean-infra
// baseline: rounds 3/4 kills coincided with sick infra; kernel passed 3
// static audits). pv: 2-phase engine, 256x128 tiles, 8 waves of 64x64,
// BK=64, K=2048 (32 K-tiles), 96KB dbuf, row-XOR swizzle, vmcnt(4),
// setprio; 256 blocks = 1 perfect round; direct fp32 epilogue.
// k_qkv (4-phase 256^2, 384 blk, round-7/8 verified), k_score (4-phase
// 256^2, 256 blk, round-8 verified), k_prep unchanged.
// Pipeline (4 dispatches):
//   1. k_prep:  xb=bf16(x); wt=bf16(W^T); rowsum=0
//   2. k_qkv:   q,k = x@W+b (bf16); v -> vT transposed  [256^2 4-phase]
//   3. k_score: P' = exp2(q@k^T*s*log2e) (bf16) + rowsum  [256^2 4-phase]
//   4. k_pv:    out = (P' @ vT^T)/rowsum (fp32 -> d_out)  [engine 256x128]
// ---------------------------------------------------------------------------

typedef __attribute__((ext_vector_type(8))) short short8;   // 8 bf16 = 4 VGPR
typedef __attribute__((ext_vector_type(4))) float f32x4;    // MFMA C/D

__device__ __forceinline__ unsigned short f2bf(float f) {
  union { float f; uint32_t u; } c; c.f = f;
  uint32_t u = c.u;
  u += 0x7FFFu + ((u >> 16) & 1u);   // RNE
  return (unsigned short)(u >> 16);
}

// async global->LDS, 16B/lane; LDS dest is wave-uniform base + lane*16.
__device__ __forceinline__ void gl16(const void* g, void* l) {
  __builtin_amdgcn_global_load_lds(
      (const __attribute__((address_space(1))) unsigned int*)g,
      (__attribute__((address_space(3))) unsigned int*)l, 16, 0, 0);
}

#define FENCE() asm volatile("" ::: "memory")
#define BARRIER() do { FENCE(); __builtin_amdgcn_s_barrier(); FENCE(); } while (0)
#define VMWAIT(n) asm volatile("s_waitcnt vmcnt(" #n ")" ::: "memory")

// ---------------- k_qkv: 256x256 tile, 512 thr, 4-phase pipeline -----------
// q,k,v = x@W+b. M=8192, N=3x1024, K=1024, BK=64 (16 K-tiles).
// 384 blocks = 32 tm x 12 zn; 128KB LDS; waves 2x4 of 128x64.
__global__ __launch_bounds__(512, 2) void k_qkv(
    const short* __restrict__ A, const short* __restrict__ B,
    short* __restrict__ Cb, short* __restrict__ vT,
    const float* __restrict__ b0, const float* __restrict__ b1,
    const float* __restrict__ b2)
{
  __shared__ short lds[65536];   // 128 KB

  const int b = blockIdx.x;          // 384
  const int xcd = b & 7, r = b >> 3; // r 0..47
  const int tm = xcd * 4 + r / 12;   // 0..31 (each XCD: 4 consecutive slabs)
  const int zn = r % 12;
  const int z = zn >> 2, tn = zn & 3;

  const int tid = threadIdx.x;
  const int lane = tid & 63;
  const int wid = tid >> 6;               // 0..7
  const int fr = lane & 15, quad = lane >> 4, frk = fr & 7;
  const int wm = wid >> 2, wn = wid & 3;  // wave: rows wm*128.., cols wn*64..

  const long tileM = (long)tm * 256;
  const long tileN = (long)tn * 256;
  const short* Az = A;
  const short* Bz = B + (long)z * 1048576L;

  const int srow = tid >> 3;
  const int sslot = (tid & 7) ^ (srow & 7);
  const short* gA = Az + (tileM + srow) * 1024 + sslot * 8;
  const short* gB = Bz + (tileN + srow) * 1024 + sslot * 8;

  const int aBase = wm << 13;             // wm*128 rows * 64 shorts
  const int bBase = 16384 + (wn << 12);   // B region + wn*64 rows
  const int o0 = ((quad ^ frk) << 3) + (fr << 6);        // kk=0 slot
  const int o1 = (((quad + 4) ^ frk) << 3) + (fr << 6);  // kk=1 slot

  f32x4 acc[8][4] = {};

  auto stageA = [&](int tt) {          // 4 loads: 256 rows of A tile tt
    const short* s = gA + tt * 64;
    short* d = &lds[(tt & 1) << 15];
    gl16(s,          d + (tid << 3));
    gl16(s + 65536,  d + 4096 + (tid << 3));
    gl16(s + 131072, d + 8192 + (tid << 3));
    gl16(s + 196608, d + 12288 + (tid << 3));
  };
  auto stageBh = [&](int tt, int h) {  // 2 loads: B rows h*128..h*128+127
    const short* s = gB + tt * 64 + h * 131072;
    short* d = &lds[((tt & 1) << 15) + 16384 + (h << 13)];
    gl16(s,         d + (tid << 3));
    gl16(s + 65536, d + 4096 + (tid << 3));
  };

  // prologue: A0(4) B0(4) A1(4); drain oldest 8, keep A1 in flight
  stageA(0); stageBh(0, 0); stageBh(0, 1); stageA(1);
  VMWAIT(4);
  BARRIER();

#pragma unroll 1
  for (int t = 0; t < 16; ++t) {
    const int bb = (t & 1) << 15;
    short8 af0[4][2], af1[4][2], bf0[2][2], bf1[2][2];

    // ---- phase 0: rows 0-63 x cols 0-31 (of wave tile)
#pragma unroll
    for (int i = 0; i < 4; ++i) {
      af0[i][0] = *(const short8*)&lds[bb + aBase + (i << 10) + o0];
      af0[i][1] = *(const short8*)&lds[bb + aBase + (i << 10) + o1];
    }
#pragma unroll
    for (int j = 0; j < 2; ++j) {
      bf0[j][0] = *(const short8*)&lds[bb + bBase + (j << 10) + o0];
      bf0[j][1] = *(const short8*)&lds[bb + bBase + (j << 10) + o1];
    }
    if (t + 1 < 16) stageBh(t + 1, 0);
    BARRIER();
    __builtin_amdgcn_s_setprio(1);
#pragma unroll
    for (int i = 0; i < 4; ++i)
#pragma unroll
      for (int j = 0; j < 2; ++j) {
        acc[i][j] = __builtin_amdgcn_mfma_f32_16x16x32_bf16(af0[i][0], bf0[j][0], acc[i][j], 0, 0, 0);
        acc[i][j] = __builtin_amdgcn_mfma_f32_16x16x32_bf16(af0[i][1], bf0[j][1], acc[i][j], 0, 0, 0);
      }
    __builtin_amdgcn_s_setprio(0);
    BARRIER();

    // ---- phase 1: rows 64-127 x cols 0-31
#pragma unroll
    for (int i = 0; i < 4; ++i) {
      af1[i][0] = *(const short8*)&lds[bb + aBase + ((i + 4) << 10) + o0];
      af1[i][1] = *(const short8*)&lds[bb + aBase + ((i + 4) << 10) + o1];
    }
    if (t + 1 < 16) stageBh(t + 1, 1);
    BARRIER();
    __builtin_amdgcn_s_setprio(1);
#pragma unroll
    for (int i = 0; i < 4; ++i)
#pragma unroll
      for (int j = 0; j < 2; ++j) {
        acc[i + 4][j] = __builtin_amdgcn_mfma_f32_16x16x32_bf16(af1[i][0], bf0[j][0], acc[i + 4][j], 0, 0, 0);
        acc[i + 4][j] = __builtin_amdgcn_mfma_f32_16x16x32_bf16(af1[i][1], bf0[j][1], acc[i + 4][j], 0, 0, 0);
      }
    __builtin_amdgcn_s_setprio(0);
    BARRIER();

    // ---- phase 2: rows 64-127 x cols 32-63
#pragma unroll
    for (int j = 0; j < 2; ++j) {
      bf1[j][0] = *(const short8*)&lds[bb + bBase + ((j + 2) << 10) + o0];
      bf1[j][1] = *(const short8*)&lds[bb + bBase + ((j + 2) << 10) + o1];
    }
    BARRIER();
    __builtin_amdgcn_s_setprio(1);
#pragma unroll
    for (int i = 0; i < 4; ++i)
#pragma unroll
      for (int j = 0; j < 2; ++j) {
        acc[i + 4][j + 2] = __builtin_amdgcn_mfma_f32_16x16x32_bf16(af1[i][0], bf1[j][0], acc[i + 4][j + 2], 0, 0, 0);
        acc[i + 4][j + 2] = __builtin_amdgcn_mfma_f32_16x16x32_bf16(af1[i][1], bf1[j][1], acc[i + 4][j + 2], 0, 0, 0);
      }
    __builtin_amdgcn_s_setprio(0);
    BARRIER();

    // ---- phase 3: rows 0-63 x cols 32-63; stage A(t+2)
    if (t + 2 < 16) stageA(t + 2);
    BARRIER();
    __builtin_amdgcn_s_setprio(1);
#pragma unroll
    for (int i = 0; i < 4; ++i)
#pragma unroll
      for (int j = 0; j < 2; ++j) {
        acc[i][j + 2] = __builtin_amdgcn_mfma_f32_16x16x32_bf16(af0[i][0], bf1[j][0], acc[i][j + 2], 0, 0, 0);
        acc[i][j + 2] = __builtin_amdgcn_mfma_f32_16x16x32_bf16(af0[i][1], bf1[j][1], acc[i][j + 2], 0, 0, 0);
      }
    __builtin_amdgcn_s_setprio(0);
    if (t < 14) { VMWAIT(4); } else { VMWAIT(0); }
    BARRIER();
  }

  __syncthreads();
  // C/D layout: row=(lane>>4)*4+rr, col=lane&15. Two passes of 64 rows.
  short* scr = &lds[wid * 4608];   // [64][72] per wave
  if (z == 2) {
    // v-tile: bias, transposed scratch [d][t], store vT[b][d][t]
    const int gb = tm >> 3;
#pragma unroll
    for (int pass = 0; pass < 2; ++pass) {
#pragma unroll
      for (int j = 0; j < 4; ++j) {
        const float bv = b2[tileN + wn * 64 + j * 16 + fr];
#pragma unroll
        for (int i = 0; i < 4; ++i)
#pragma unroll
          for (int rr = 0; rr < 4; ++rr)
            scr[(j * 16 + fr) * 72 + i * 16 + quad * 4 + rr] =
                (short)f2bf(acc[pass * 4 + i][j][rr] + bv);
      }
      const long t0 = (long)(tm & 7) * 256 + wm * 128 + pass * 64;
#pragma unroll
      for (int c = 0; c < 8; ++c) {
        const int rr = c * 8 + (lane >> 3);
        const int cc = (lane & 7) * 8;
        short8 v = *(const short8*)&scr[rr * 72 + cc];
        const long gd = tileN + wn * 64 + rr;
        *(short8*)(vT + ((long)gb << 21) + gd * 2048 + t0 + cc) = v;
      }
      if (pass == 0) __syncthreads();   // scratch WAR between passes
    }
  } else {
    short* C = Cb + (long)z * 8388608L;
    const float* bias = (z == 0) ? b0 : b1;
#pragma unroll
    for (int pass = 0; pass < 2; ++pass) {
#pragma unroll
      for (int j = 0; j < 4; ++j) {
        const float bv = bias[tileN + wn * 64 + j * 16 + fr];
#pragma unroll
        for (int i = 0; i < 4; ++i)
#pragma unroll
          for (int rr = 0; rr < 4; ++rr)
            scr[(i * 16 + quad * 4 + rr) * 72 + j * 16 + fr] =
                (short)f2bf(acc[pass * 4 + i][j][rr] + bv);
      }
#pragma unroll
      for (int c = 0; c < 8; ++c) {
        const int row = c * 8 + (lane >> 3);
        const int col = (lane & 7) * 8;
        short8 v = *(const short8*)&scr[row * 72 + col];
        *(short8*)(C + (tileM + wm * 128 + pass * 64 + row) * 1024 +
                   tileN + wn * 64 + col) = v;
      }
      if (pass == 0) __syncthreads();   // scratch WAR between passes
    }
  }
}

// ---------------- k_score: 256x256 tile, 512 thr, 4-phase pipeline ---------
// P' = exp2(q@k^T * scale) bf16 + rowsum atomics. K=1024, BK=64.
// Grid 256 blocks (1/CU, exactly 1 round): xcd=b&7; 32 (z,tm) slabs x 8 tn.
__global__ __launch_bounds__(512, 2) void k_score(
    const short* __restrict__ A, const short* __restrict__ B,
    short* __restrict__ Pp, float scale, float* __restrict__ rowsum)
{
  __shared__ short lds[65536];   // 128 KB

  const int b = blockIdx.x;
  const int xcd = b & 7, jb = b >> 3;
  const int p = xcd * 4 + (jb >> 3);   // 32 (z,tm) slabs, 4 per XCD
  const int tn = jb & 7;
  const int z = p >> 3, tm = p & 7;

  const int tid = threadIdx.x;
  const int lane = tid & 63;
  const int wid = tid >> 6;            // 0..7
  const int fr = lane & 15, quad = lane >> 4;
  const int wm = wid >> 2, wn = wid & 3;   // wave owns rows wm*128.., cols wn*64..

  const long tileM = (long)tm * 256;
  const long tileN = (long)tn * 256;
  const short* Az = A + (long)z * 2097152L;
  const short* Bz = B + (long)z * 2097152L;

  const int srow = tid >> 3;
  const int sslot = (tid & 7) ^ (srow & 7);
  const short* gA = Az + (tileM + srow) * 1024 + sslot * 8;
  const short* gB = Bz + (tileN + srow) * 1024 + sslot * 8;

  const int frk = fr & 7;
  const int aBase = wm << 13;                                 // own A half
  const int bRow  = 16384 + ((wn >> 1) << 13) + ((wn & 1) << 12); // own B half+64
  const int o0 = ((quad ^ frk) << 3) + (fr << 6);             // kk=0 slot
  const int o1 = (((quad + 4) ^ frk) << 3) + (fr << 6);       // kk=1 slot

  f32x4 acc[8][4] = {};

  auto stageA = [&](int tt) {          // 4 loads: both halves of A tile tt
    const short* s = gA + tt * 64;
    short* d = &lds[(tt & 1) << 15];
    gl16(s,          d + (tid << 3));
    gl16(s + 65536,  d + 4096 + (tid << 3));
    gl16(s + 131072, d + 8192 + (tid << 3));
    gl16(s + 196608, d + 12288 + (tid << 3));
  };
  auto stageBh = [&](int tt, int h) {  // 2 loads: B half h of tile tt
    const short* s = gB + tt * 64 + h * 131072;
    short* d = &lds[((tt & 1) << 15) + 16384 + (h << 13)];
    gl16(s,         d + (tid << 3));
    gl16(s + 65536, d + 4096 + (tid << 3));
  };

  // prologue: A0(4) B0(4) A1(4); drain oldest 8, keep A1 in flight
  stageA(0); stageBh(0, 0); stageBh(0, 1); stageA(1);
  VMWAIT(4);
  BARRIER();

#pragma unroll 1
  for (int t = 0; t < 16; ++t) {
    const int bb = (t & 1) << 15;
    short8 af0[4][2], af1[4][2], bf0[2][2], bf1[2][2];

    // ---- phase 0: quadrant rows 0-63 x cols 0-31 (of wave tile)
#pragma unroll
    for (int i = 0; i < 4; ++i) {
      af0[i][0] = *(const short8*)&lds[bb + aBase + (i << 10) + o0];
      af0[i][1] = *(const short8*)&lds[bb + aBase + (i << 10) + o1];
    }
#pragma unroll
    for (int j = 0; j < 2; ++j) {
      bf0[j][0] = *(const short8*)&lds[bb + bRow + (j << 10) + o0];
      bf0[j][1] = *(const short8*)&lds[bb + bRow + (j << 10) + o1];
    }
    if (t + 1 < 16) stageBh(t + 1, 0);
    BARRIER();
    __builtin_amdgcn_s_setprio(1);
#pragma unroll
    for (int i = 0; i < 4; ++i)
#pragma unroll
      for (int j = 0; j < 2; ++j) {
        acc[i][j] = __builtin_amdgcn_mfma_f32_16x16x32_bf16(af0[i][0], bf0[j][0], acc[i][j], 0, 0, 0);
        acc[i][j] = __builtin_amdgcn_mfma_f32_16x16x32_bf16(af0[i][1], bf0[j][1], acc[i][j], 0, 0, 0);
      }
    __builtin_amdgcn_s_setprio(0);
    BARRIER();

    // ---- phase 1: rows 64-127 x cols 0-31
#pragma unroll
    for (int i = 0; i < 4; ++i) {
      af1[i][0] = *(const short8*)&lds[bb + aBase + ((i + 4) << 10) + o0];
      af1[i][1] = *(const short8*)&lds[bb + aBase + ((i + 4) << 10) + o1];
    }
    if (t + 1 < 16) stageBh(t + 1, 1);
    BARRIER();
    __builtin_amdgcn_s_setprio(1);
#pragma unroll
    for (int i = 0; i < 4; ++i)
#pragma unroll
      for (int j = 0; j < 2; ++j) {
        acc[i + 4][j] = __builtin_amdgcn_mfma_f32_16x16x32_bf16(af1[i][0], bf0[j][0], acc[i + 4][j], 0, 0, 0);
        acc[i + 4][j] = __builtin_amdgcn_mfma_f32_16x16x32_bf16(af1[i][1], bf0[j][1], acc[i + 4][j], 0, 0, 0);
      }
    __builtin_amdgcn_s_setprio(0);
    BARRIER();

    // ---- phase 2: rows 64-127 x cols 32-63
#pragma unroll
    for (int j = 0; j < 2; ++j) {
      bf1[j][0] = *(const short8*)&lds[bb + bRow + ((j + 2) << 10) + o0];
      bf1[j][1] = *(const short8*)&lds[bb + bRow + ((j + 2) << 10) + o1];
    }
    BARRIER();
    __builtin_amdgcn_s_setprio(1);
#pragma unroll
    for (int i = 0; i < 4; ++i)
#pragma unroll
      for (int j = 0; j < 2; ++j) {
        acc[i + 4][j + 2] = __builtin_amdgcn_mfma_f32_16x16x32_bf16(af1[i][0], bf1[j][0], acc[i + 4][j + 2], 0, 0, 0);
        acc[i + 4][j + 2] = __builtin_amdgcn_mfma_f32_16x16x32_bf16(af1[i][1], bf1[j][1], acc[i + 4][j + 2], 0, 0, 0);
      }
    __builtin_amdgcn_s_setprio(0);
    BARRIER();

    // ---- phase 3: rows 0-63 x cols 32-63; stage A(t+2)
    if (t + 2 < 16) stageA(t + 2);
    BARRIER();
    __builtin_amdgcn_s_setprio(1);
#pragma unroll
    for (int i = 0; i < 4; ++i)
#pragma unroll
      for (int j = 0; j < 2; ++j) {
        acc[i][j + 2] = __builtin_amdgcn_mfma_f32_16x16x32_bf16(af0[i][0], bf1[j][0], acc[i][j + 2], 0, 0, 0);
        acc[i][j + 2] = __builtin_amdgcn_mfma_f32_16x16x32_bf16(af0[i][1], bf1[j][1], acc[i][j + 2], 0, 0, 0);
      }
    __builtin_amdgcn_s_setprio(0);
    if (t < 14) { VMWAIT(4); } else { VMWAIT(0); }
    BARRIER();
  }

  // exp2 (register-only)
#pragma unroll
  for (int i = 0; i < 8; ++i)
#pragma unroll
    for (int j = 0; j < 4; ++j)
#pragma unroll
      for (int r = 0; r < 4; ++r)
        acc[i][j][r] = exp2f(acc[i][j][r] * scale);

  // rowsum partials
  float* rsz = rowsum + (long)z * 2048 + tileM + wm * 128;
#pragma unroll
  for (int i = 0; i < 8; ++i)
#pragma unroll
    for (int r = 0; r < 4; ++r) {
      float s = acc[i][0][r] + acc[i][1][r] + acc[i][2][r] + acc[i][3][r];
      s += __shfl_xor(s, 1);
      s += __shfl_xor(s, 2);
      s += __shfl_xor(s, 4);
      s += __shfl_xor(s, 8);
      if (fr == 0) atomicAdd(&rsz[i * 16 + quad * 4 + r], s);
    }

  // bf16 store via per-wave LDS transpose scratch
  __syncthreads();
  short* C = Pp + (long)z * 4194304L;
  short* scr = &lds[wid * 4608];   // [64][72] per wave
#pragma unroll
  for (int pass = 0; pass < 2; ++pass) {
#pragma unroll
    for (int j = 0; j < 4; ++j)
#pragma unroll
      for (int i = 0; i < 4; ++i)
#pragma unroll
        for (int r = 0; r < 4; ++r)
          scr[(i * 16 + quad * 4 + r) * 72 + j * 16 + fr] =
              (short)f2bf(acc[pass * 4 + i][j][r]);
#pragma unroll
    for (int c = 0; c < 8; ++c) {
      const int row = c * 8 + (lane >> 3);
      const int col = (lane & 7) * 8;
      short8 v = *(const short8*)&scr[row * 72 + col];
      *(short8*)(C + (tileM + wm * 128 + pass * 64 + row) * 2048 +
                 tileN + wn * 64 + col) = v;
    }
  }
}

// ---------------- k_pv: 256x128 tile, 512 thr, 2-phase engine --------------
// out = (P' @ vT^T) / rowsum, fp32. M=2048, N=1024, K=2048 per z, BK=64.
// 256 blocks = 8tm x 8tn x 4z, exactly 1 round. LDS 96KB dbuf, row-XOR
// swizzle, counted vmcnt(4), setprio. Direct fp32 epilogue.
__global__ __launch_bounds__(512, 2) void k_pv(
    const short* __restrict__ A, const short* __restrict__ B,
    float* __restrict__ Cf, float* __restrict__ rowsum)
{
  __shared__ short lds[49152];   // 96 KB

  const int b = blockIdx.x;            // 256
  const int xcd = b & 7, jb = b >> 3;  // jb 0..31
  const int p = xcd * 4 + (jb >> 3);   // 32 (z,tm) slabs, 4 per XCD
  const int tn = jb & 7;
  const int z = p >> 3, tm = p & 7;

  const int tid = threadIdx.x;
  const int lane = tid & 63;
  const int wid = tid >> 6;               // 0..7
  const int fr = lane & 15, quad = lane >> 4, frk = fr & 7;
  const int wm = wid >> 1, wn = wid & 1;  // wave: rows wm*64.., cols wn*64..

  const long tileM = (long)tm * 256;
  const long tileN = (long)tn * 128;
  const short* Az = A + (long)z * 4194304L;   // P' [2048][2048]
  const short* Bz = B + (long)z * 2097152L;   // vT [1024][2048]

  // staging: chunk c -> (row=c>>3, slot=(c&7)^(row&7)); K-row stride 2048.
  const int srow = tid >> 3;
  const int sslot = (tid & 7) ^ (srow & 7);
  const short* gA = Az + (tileM + srow) * 2048 + sslot * 8;
  const short* gB = Bz + (tileN + srow) * 2048 + sslot * 8;

  const int aBase = wm << 12;             // wm*64 rows * 64 shorts
  const int bBase = 16384 + (wn << 12);   // B region + wn*64 rows
  const int o0 = ((quad ^ frk) << 3) + (fr << 6);        // kk=0 slot
  const int o1 = (((quad + 4) ^ frk) << 3) + (fr << 6);  // kk=1 slot

  f32x4 acc[4][4] = {};

  auto stageA = [&](int tt) {          // 4 loads: 256 rows of A tile tt
    const short* s = gA + tt * 64;
    short* d = &lds[(tt & 1) * 24576];
    gl16(s,          d + (tid << 3));
    gl16(s + 131072, d + 4096 + (tid << 3));   // +64 rows * 2048
    gl16(s + 262144, d + 8192 + (tid << 3));
    gl16(s + 393216, d + 12288 + (tid << 3));
  };
  auto stageB = [&](int tt) {          // 2 loads: 128 rows of B tile tt
    const short* s = gB + tt * 64;
    short* d = &lds[(tt & 1) * 24576 + 16384];
    gl16(s,          d + (tid << 3));
    gl16(s + 131072, d + 4096 + (tid << 3));
  };

  // prologue: A0(4) B0(2) A1(4); drain A0+B0, keep A1 in flight
  stageA(0); stageB(0); stageA(1);
  VMWAIT(4);
  BARRIER();

#pragma unroll 1
  for (int t = 0; t < 32; ++t) {
    const int bb = (t & 1) * 24576;
    short8 af[4][2], bf0[2][2], bf1[2][2];

    // ---- phase 0: all rows x cols 0-31 (of wave tile)
#pragma unroll
    for (int i = 0; i < 4; ++i) {
      af[i][0] = *(const short8*)&lds[bb + aBase + (i << 10) + o0];
      af[i][1] = *(const short8*)&lds[bb + aBase + (i << 10) + o1];
    }
#pragma unroll
    for (int j = 0; j < 2; ++j) {
      bf0[j][0] = *(const short8*)&lds[bb + bBase + (j << 10) + o0];
      bf0[j][1] = *(const short8*)&lds[bb + bBase + (j << 10) + o1];
    }
    if (t + 1 < 32) stageB(t + 1);
    BARRIER();
    __builtin_amdgcn_s_setprio(1);
#pragma unroll
    for (int i = 0; i < 4; ++i)
#pragma unroll
      for (int j = 0; j < 2; ++j) {
        acc[i][j] = __builtin_amdgcn_mfma_f32_16x16x32_bf16(af[i][0], bf0[j][0], acc[i][j], 0, 0, 0);
        acc[i][j] = __builtin_amdgcn_mfma_f32_16x16x32_bf16(af[i][1], bf0[j][1], acc[i][j], 0, 0, 0);
      }
    __builtin_amdgcn_s_setprio(0);
    BARRIER();

    // ---- phase 1: all rows x cols 32-63; stage A(t+2)
#pragma unroll
    for (int j = 0; j < 2; ++j) {
      bf1[j][0] = *(const short8*)&lds[bb + bBase + ((j + 2) << 10) + o0];
      bf1[j][1] = *(const short8*)&lds[bb + bBase + ((j + 2) << 10) + o1];
    }
    if (t + 2 < 32) stageA(t + 2);
    BARRIER();
    __builtin_amdgcn_s_setprio(1);
#pragma unroll
    for (int i = 0; i < 4; ++i)
#pragma unroll
      for (int j = 0; j < 2; ++j) {
        acc[i][j + 2] = __builtin_amdgcn_mfma_f32_16x16x32_bf16(af[i][0], bf1[j][0], acc[i][j + 2], 0, 0, 0);
        acc[i][j + 2] = __builtin_amdgcn_mfma_f32_16x16x32_bf16(af[i][1], bf1[j][1], acc[i][j + 2], 0, 0, 0);
      }
    __builtin_amdgcn_s_setprio(0);
    // tile boundary: drain A(t+1)+B(t+1), keep A(t+2) (4 loads) in flight.
    if (t < 30) { VMWAIT(4); } else { VMWAIT(0); }
    BARRIER();
  }

  // direct fp32 epilogue: row=(lane>>4)*4+r, col=lane&15 (C/D layout)
  float* C = Cf + (long)z * 2097152L;
  const float* rsz = rowsum + (long)z * 2048 + tileM + wm * 64;
#pragma unroll
  for (int i = 0; i < 4; ++i)
#pragma unroll
    for (int r = 0; r < 4; ++r) {
      const int lr = i * 16 + quad * 4 + r;
      const long gr = tileM + wm * 64 + lr;
      const float rinv = 1.0f / rsz[lr];
#pragma unroll
      for (int j = 0; j < 4; ++j)
        C[gr * 1024 + tileN + wn * 64 + j * 16 + fr] = acc[i][j][r] * rinv;
    }
}

// prep: blocks [0,8192) cvt x -> bf16; [8192,11264) W^T -> bf16; 11264 zero rs
__global__ __launch_bounds__(256) void k_prep(
    const float4* __restrict__ x, ushort4* __restrict__ xb,
    const float* __restrict__ Wq, const float* __restrict__ Wk,
    const float* __restrict__ Wv, short* __restrict__ WT,
    float* __restrict__ rs)
{
  __shared__ short tile[32][33];
  const int b = blockIdx.x;
  if (b < 8192) {
    const long i = (long)b * 256 + threadIdx.x;
    float4 v = x[i];
    ushort4 o;
    o.x = f2bf(v.x); o.y = f2bf(v.y); o.z = f2bf(v.z); o.w = f2bf(v.w);
    xb[i] = o;
  } else if (b < 11264) {
    const int idx = b - 8192;
    const int z = idx >> 10, rem = idx & 1023;
    const float* W = (z == 0) ? Wq : ((z == 1) ? Wk : Wv);
    short* d = WT + (long)z * 1024 * 1024;
    const int n0 = (rem & 31) * 32, d0 = (rem >> 5) * 32;
    const int tx = threadIdx.x & 31, ty = threadIdx.x >> 5;
#pragma unroll
    for (int p = 0; p < 4; ++p)
      tile[ty + p * 8][tx] = (short)f2bf(W[(long)(d0 + ty + p * 8) * 1024 + n0 + tx]);
    __syncthreads();
#pragma unroll
    for (int p = 0; p < 4; ++p)
      d[(long)(n0 + ty + p * 8) * 1024 + d0 + tx] = tile[tx][ty + p * 8];
  } else {
#pragma unroll
    for (int p = 0; p < 32; ++p)
      rs[p * 256 + threadIdx.x] = 0.0f;
  }
}

extern "C" void kernel_launch(void* const* d_in, const int* in_sizes, int n_in,
                              void* d_out, int out_size, void* d_ws, size_t ws_size,
                              hipStream_t stream) {
  const float* x  = (const float*)d_in[0];
  const float* Wq = (const float*)d_in[1];
  const float* bq = (const float*)d_in[2];
  const float* Wk = (const float*)d_in[3];
  const float* bk = (const float*)d_in[4];
  const float* Wv = (const float*)d_in[5];
  const float* bv = (const float*)d_in[6];

  char* ws = (char*)d_ws;
  short* xb  = (short*)(ws);                  // 16 MB
  short* wt  = (short*)(ws + 16777216);       // 6 MB
  short* qkv = (short*)(ws + 23068672);       // 48 MB: q | k | vT
  short* Pp  = (short*)(ws + 73400320);       // 32 MB: [4][2048][2048] bf16
  float* rs  = (float*)(ws + 106954752);      // 32 KB: [4][2048] fp32
  short* vT  = qkv + 2L * 8388608;            // [4][1024][2048] bf16

  // 1. prep: xb, wt, rowsum=0
  k_prep<<<11265, 256, 0, stream>>>((const float4*)x, (ushort4*)xb,
                                    Wq, Wk, Wv, wt, rs);
  // 2. q,k = x@W+b (bf16); v written transposed into vT  [256^2 4-phase]
  k_qkv<<<384, 512, 0, stream>>>(xb, wt, qkv, vT, bq, bk, bv);
  // 3. P' = exp2(q@k^T * scale*log2e), bf16 + rowsum  [256^2 4-phase]
  k_score<<<256, 512, 0, stream>>>(qkv, qkv + 8388608, Pp,
                                   0.03125f * 1.44269504088896f, rs);
  // 4. out = (P' @ vT^T) / rowsum  (fp32 -> d_out)  [engine 256x128]
  k_pv<<<256, 512, 0, stream>>>(Pp, vT, (float*)d_out, rs);
}